// Round 12
// baseline (213.987 us; speedup 1.0000x reference)
//
#include <hip/hip_runtime.h>
#include <hip/hip_bf16.h>
#include <cstdint>
#include <cstddef>

#define B_ 4
#define S_ 2048
#define D_ 1024
#define H_ 16
#define DK_ 64
#define NTOK (B_*S_)

typedef __bf16 bf16;
typedef __bf16 bf16x8 __attribute__((ext_vector_type(8)));
typedef short s16x4 __attribute__((ext_vector_type(4)));
typedef float f32x4 __attribute__((ext_vector_type(4)));

#define AS1 __attribute__((address_space(1)))
#define AS3 __attribute__((address_space(3)))

static __device__ __forceinline__ short f2bf_s(float f) {
    return __builtin_bit_cast(short, (__bf16)f);
}

static __device__ __forceinline__ f32x4 mfma16(s16x4 a, s16x4 b, f32x4 c) {
#if __has_builtin(__builtin_amdgcn_mfma_f32_16x16x16bf16_1k)
    return __builtin_amdgcn_mfma_f32_16x16x16bf16_1k(a, b, c, 0, 0, 0);
#else
    asm volatile("v_mfma_f32_16x16x16_bf16 %0, %1, %2, %0\n\ts_nop 7\n\ts_nop 7"
                 : "+v"(c) : "v"(a), "v"(b));
    return c;
#endif
}

// ---------------- fused fp32 -> bf16 convert: [X | Wq | Wk | Wv | Wo] ----------------
__global__ void cvt_all(const float* __restrict__ x, const float* __restrict__ wq,
                        const float* __restrict__ wk, const float* __restrict__ wv,
                        const float* __restrict__ wo, bf16* __restrict__ dst) {
    const int NX8 = NTOK * D_ / 8;
    const int W8 = D_ * D_ / 8;          // 131072 = 2^17
    int i = blockIdx.x * blockDim.x + threadIdx.x;
    if (i >= NX8 + 4 * W8) return;
    const float* src; int j;
    if (i < NX8) { src = x; j = i; }
    else {
        int k = i - NX8;
        int w = k >> 17;
        j = k & (W8 - 1);
        src = w == 0 ? wq : (w == 1 ? wk : (w == 2 ? wv : wo));
    }
    const float4* s4 = reinterpret_cast<const float4*>(src) + (size_t)j * 2;
    float4 a = s4[0], b = s4[1];
    bf16x8 o;
    o[0] = (bf16)a.x; o[1] = (bf16)a.y; o[2] = (bf16)a.z; o[3] = (bf16)a.w;
    o[4] = (bf16)b.x; o[5] = (bf16)b.y; o[6] = (bf16)b.z; o[7] = (bf16)b.w;
    reinterpret_cast<bf16x8*>(dst)[i] = o;
}

// ---------------- RoPE cos/sin table: [NTOK][32] float2 ----------------
__global__ void rope_table(const int* __restrict__ pos, float2* __restrict__ tab) {
    int i = blockIdx.x * blockDim.x + threadIdx.x;
    if (i >= NTOK * 32) return;
    int n = i >> 5, p = i & 31;
    float pf = (float)pos[n];
    float freq = powf(10000.0f, -(float)p * (1.0f / 32.0f));
    float ang = pf * freq;
    float s, c;
    sincosf(ang, &s, &c);
    tab[i] = make_float2(c, s);
}

// ---------------- 128x128 QKV GEMM: writes Q plain+RoPE+scale, K pre-swizzled,
// V transposed+pre-swizzled (flash consumes K/V via bare global_load_lds).
__global__ __launch_bounds__(256, 2)
void gemm_qkv(const bf16* __restrict__ A, const bf16* __restrict__ Bw,
              bf16* __restrict__ Qr, bf16* __restrict__ Kz, bf16* __restrict__ VT,
              const float2* __restrict__ tab) {
    const float SCL2E = 0.125f * 1.44269504088896340736f;
    constexpr int NKT = 16;
    __shared__ alignas(16) bf16 lds[2][(128 + 128) * 64];
    const int tid = threadIdx.x;
    const int lane = tid & 63;
    const int wid = tid >> 6;
    const int wm = wid >> 1, wn = wid & 1;
    const int lr = lane & 15, lg = lane >> 4;
    const int m0 = blockIdx.x * 128;
    const int n0g = blockIdx.y * 128;             // 0..3071

    f32x4 acc[4][4] = {};

    auto stage = [&](int kt, int bufi) {
        bf16* dst = &lds[bufi][0];
#pragma unroll
        for (int j = 0; j < 4; ++j) {
            int flat = j * 256 + tid;
            int r = flat >> 3, c = flat & 7;
            const bf16* src = A + (size_t)(m0 + r) * 1024 + kt * 64 + ((c ^ (r & 7)) << 3);
            __builtin_amdgcn_global_load_lds((const AS1 uint32_t*)src,
                                             (AS3 uint32_t*)(dst + (size_t)flat * 8), 16, 0, 0);
        }
#pragma unroll
        for (int j = 0; j < 4; ++j) {
            int flat = j * 256 + tid;
            int r = flat >> 3, c = flat & 7;
            const bf16* src = Bw + (size_t)(n0g + r) * 1024 + kt * 64 + ((c ^ (r & 7)) << 3);
            __builtin_amdgcn_global_load_lds((const AS1 uint32_t*)src,
                                             (AS3 uint32_t*)(dst + 128 * 64 + (size_t)flat * 8), 16, 0, 0);
        }
    };

    stage(0, 0);

    for (int kt = 0; kt < NKT; ++kt) {
        const bf16* bufA = &lds[kt & 1][0];
        const bf16* bufB = bufA + 128 * 64;

        asm volatile("" ::: "memory");
        __builtin_amdgcn_s_barrier();
        asm volatile("" ::: "memory");
        if (kt + 1 < NKT) {
            stage(kt + 1, (kt + 1) & 1);
            asm volatile("s_waitcnt vmcnt(8)" ::: "memory");
        } else {
            asm volatile("s_waitcnt vmcnt(0)" ::: "memory");
        }
        __builtin_amdgcn_s_barrier();
        asm volatile("" ::: "memory");

        const int sx = lr & 7;
        bf16x8 af[4][2], bfr[4][2];
#pragma unroll
        for (int mf = 0; mf < 4; ++mf)
#pragma unroll
            for (int kh = 0; kh < 2; ++kh)
                af[mf][kh] = *reinterpret_cast<const bf16x8*>(
                    &bufA[(wm * 64 + mf * 16 + lr) * 64 + (((kh * 4 + lg) ^ sx) << 3)]);
#pragma unroll
        for (int nf = 0; nf < 4; ++nf)
#pragma unroll
            for (int kh = 0; kh < 2; ++kh)
                bfr[nf][kh] = *reinterpret_cast<const bf16x8*>(
                    &bufB[(wn * 64 + nf * 16 + lr) * 64 + (((kh * 4 + lg) ^ sx) << 3)]);
        __builtin_amdgcn_s_setprio(1);
#pragma unroll
        for (int mf = 0; mf < 4; ++mf)
#pragma unroll
            for (int nf = 0; nf < 4; ++nf)
#pragma unroll
                for (int kh = 0; kh < 2; ++kh)
                    acc[mf][nf] = __builtin_amdgcn_mfma_f32_16x16x32_bf16(af[mf][kh], bfr[nf][kh], acc[mf][nf], 0, 0, 0);
        __builtin_amdgcn_s_setprio(0);
    }

    // epilogue
#pragma unroll
    for (int mf = 0; mf < 4; ++mf) {
#pragma unroll
        for (int nf = 0; nf < 4; ++nf) {
            int row0 = m0 + wm * 64 + mf * 16 + lg * 4;      // +r
            int colg = n0g + wn * 64 + nf * 16 + lr;
            int which = colg >> 10;                          // block-uniform
            int col = colg & 1023;
            if (which < 2) {
                // Q / K: RoPE (pairs are lane^1); Q additionally pre-scaled
#pragma unroll
                for (int r = 0; r < 4; ++r) {
                    int row = row0 + r;
                    float v = acc[mf][nf][r];
                    float partner = __shfl_xor(v, 1, 64);
                    float2 cs = tab[(size_t)row * 32 + ((col >> 1) & 31)];
                    float o = (col & 1) ? fmaf(v, cs.x, partner * cs.y)
                                        : fmaf(v, cs.x, -partner * cs.y);
                    if (which == 0) {
                        Qr[(size_t)row * 1024 + col] = (bf16)(o * SCL2E);
                    } else {
                        // K: swizzle col within head slice: e' = e ^ ((token&7)<<3)
                        int h = col >> 6, e = col & 63;
                        int e2 = e ^ ((row & 7) << 3);
                        Kz[(size_t)row * 1024 + h * 64 + e2] = (bf16)o;
                    }
                }
            } else {
                // V: transposed + swizzled VT[b][h][tile][dd][kv ^ swz(dd)], 8B packed
                int h = col >> 6, dd = col & 63;
                int kvb = row0 & 63;                          // aligned 4
                int sw = (((dd & 7) ^ ((dd >> 3) & 7)) & 7) << 3;
                s16x4 pk;
#pragma unroll
                for (int r = 0; r < 4; ++r) pk[r] = f2bf_s(acc[mf][nf][r]);
                size_t addr = ((((size_t)((row0 >> 11) * 16 + h)) * 32 + ((row0 >> 6) & 31)) * 64 + dd) * 64
                              + (size_t)(kvb ^ sw);
                *reinterpret_cast<s16x4*>(&VT[addr]) = pk;
            }
        }
    }
}

// ---------------- output GEMM: 128x128, fp32 out (unchanged from R10) ----------------
__global__ __launch_bounds__(256, 2)
void gemm_out(const bf16* __restrict__ A, const bf16* __restrict__ Bw,
              float* __restrict__ Cp) {
    constexpr int NKT = 16;
    __shared__ alignas(16) bf16 lds[2][(128 + 128) * 64];
    const int tid = threadIdx.x;
    const int lane = tid & 63;
    const int wid = tid >> 6;
    const int wm = wid >> 1, wn = wid & 1;
    const int lr = lane & 15, lg = lane >> 4;
    const int m0 = blockIdx.x * 128;
    const int n0g = blockIdx.y * 128;

    f32x4 acc[4][4] = {};

    auto stage = [&](int kt, int bufi) {
        bf16* dst = &lds[bufi][0];
#pragma unroll
        for (int j = 0; j < 4; ++j) {
            int flat = j * 256 + tid;
            int r = flat >> 3, c = flat & 7;
            const bf16* src = A + (size_t)(m0 + r) * 1024 + kt * 64 + ((c ^ (r & 7)) << 3);
            __builtin_amdgcn_global_load_lds((const AS1 uint32_t*)src,
                                             (AS3 uint32_t*)(dst + (size_t)flat * 8), 16, 0, 0);
        }
#pragma unroll
        for (int j = 0; j < 4; ++j) {
            int flat = j * 256 + tid;
            int r = flat >> 3, c = flat & 7;
            const bf16* src = Bw + (size_t)(n0g + r) * 1024 + kt * 64 + ((c ^ (r & 7)) << 3);
            __builtin_amdgcn_global_load_lds((const AS1 uint32_t*)src,
                                             (AS3 uint32_t*)(dst + 128 * 64 + (size_t)flat * 8), 16, 0, 0);
        }
    };

    stage(0, 0);

    for (int kt = 0; kt < NKT; ++kt) {
        const bf16* bufA = &lds[kt & 1][0];
        const bf16* bufB = bufA + 128 * 64;

        asm volatile("" ::: "memory");
        __builtin_amdgcn_s_barrier();
        asm volatile("" ::: "memory");
        if (kt + 1 < NKT) {
            stage(kt + 1, (kt + 1) & 1);
            asm volatile("s_waitcnt vmcnt(8)" ::: "memory");
        } else {
            asm volatile("s_waitcnt vmcnt(0)" ::: "memory");
        }
        __builtin_amdgcn_s_barrier();
        asm volatile("" ::: "memory");

        const int sx = lr & 7;
        bf16x8 af[4][2], bfr[4][2];
#pragma unroll
        for (int mf = 0; mf < 4; ++mf)
#pragma unroll
            for (int kh = 0; kh < 2; ++kh)
                af[mf][kh] = *reinterpret_cast<const bf16x8*>(
                    &bufA[(wm * 64 + mf * 16 + lr) * 64 + (((kh * 4 + lg) ^ sx) << 3)]);
#pragma unroll
        for (int nf = 0; nf < 4; ++nf)
#pragma unroll
            for (int kh = 0; kh < 2; ++kh)
                bfr[nf][kh] = *reinterpret_cast<const bf16x8*>(
                    &bufB[(wn * 64 + nf * 16 + lr) * 64 + (((kh * 4 + lg) ^ sx) << 3)]);
        __builtin_amdgcn_s_setprio(1);
#pragma unroll
        for (int mf = 0; mf < 4; ++mf)
#pragma unroll
            for (int nf = 0; nf < 4; ++nf)
#pragma unroll
                for (int kh = 0; kh < 2; ++kh)
                    acc[mf][nf] = __builtin_amdgcn_mfma_f32_16x16x32_bf16(af[mf][kh], bfr[nf][kh], acc[mf][nf], 0, 0, 0);
        __builtin_amdgcn_s_setprio(0);
    }

#pragma unroll
    for (int mf = 0; mf < 4; ++mf)
#pragma unroll
        for (int nf = 0; nf < 4; ++nf)
#pragma unroll
            for (int r = 0; r < 4; ++r) {
                int row = m0 + wm * 64 + mf * 16 + lg * 4 + r;
                int colg = n0g + wn * 64 + nf * 16 + lr;
                Cp[(size_t)row * 1024 + colg] = acc[mf][nf][r];
            }
}

// ---------------- causal flash attention: gload_lds staging, paired 128-row strips ----
// grid (8, 64). Per-tile math identical to R10-verified flash_attn5; staging replaced
// by 4 global_load_lds (K/V pre-permuted by gemm_qkv) + gemm128's counted-vmcnt
// 2-barrier skeleton. Removes 18 ds_writes + reg staging + ~30 addr VALU per tile.
__global__ __launch_bounds__(256, 2)
void flash_attn9(const bf16* __restrict__ Q, const bf16* __restrict__ Kz,
                 const bf16* __restrict__ VT, bf16* __restrict__ O) {
    __shared__ bf16 Ks[2][64 * 64];
    __shared__ bf16 Vt[2][64 * 64];
    const int tid = threadIdx.x, lane = tid & 63, w = tid >> 6;
    const int lr = lane & 15, lg = lane >> 4;
    const int qtA = blockIdx.x;
    const int qtB = 15 - qtA;
    const int q0[2] = { qtA * 128, qtB * 128 };
    const int ntS[2] = { 2 * qtA + 2, 2 * qtB + 2 };
    const int NT = ntS[1];
    const int bh = blockIdx.y;
    const int b = bh >> 4, h = bh & 15;
    const size_t base = ((size_t)b * S_) * D_ + (size_t)h * DK_;
    const size_t vtbase = (size_t)bh * 32 * 4096;            // [b*16+h][tile][dd][kv']

    bf16x8 aq[2][2][2];
#pragma unroll
    for (int si = 0; si < 2; ++si)
#pragma unroll
        for (int qs = 0; qs < 2; ++qs) {
            int qrow = q0[si] + w * 32 + qs * 16 + lr;
            const bf16* qp = Q + base + (size_t)qrow * D_ + lg * 8;
            aq[si][qs][0] = *reinterpret_cast<const bf16x8*>(qp);
            aq[si][qs][1] = *reinterpret_cast<const bf16x8*>(qp + 32);
        }

    f32x4 acc[2][2][4] = {};
    float m_run[2][2] = {{-1e30f, -1e30f}, {-1e30f, -1e30f}};
    float l_run[2][2] = {{0.f, 0.f}, {0.f, 0.f}};

    const int sjj = tid >> 3;                 // 0..31
    const int se0 = (tid & 7) * 8;            // 0..56

    auto stage = [&](int t, int bufi) {
        bf16* kd = Ks[bufi];
        bf16* vd = Vt[bufi];
#pragma unroll
        for (int i = 0; i < 2; ++i) {
            int jj = sjj + i * 32;
            const bf16* ksrc = Kz + base + (size_t)(t * 64 + jj) * 1024 + se0;
            __builtin_amdgcn_global_load_lds((const AS1 uint32_t*)ksrc,
                                             (AS3 uint32_t*)(kd + jj * 64 + se0), 16, 0, 0);
            const bf16* vsrc = VT + vtbase + (size_t)t * 4096 + jj * 64 + se0;
            __builtin_amdgcn_global_load_lds((const AS1 uint32_t*)vsrc,
                                             (AS3 uint32_t*)(vd + jj * 64 + se0), 16, 0, 0);
        }
    };

    stage(0, 0);

    for (int t = 0; t < NT; ++t) {
        const int j0 = t * 64;
        const bf16* KsB = Ks[t & 1];
        const bf16* VtB = Vt[t & 1];

        asm volatile("" ::: "memory");
        __builtin_amdgcn_s_barrier();          // BAR-A: readers of buf[(t+1)&1] done
        asm volatile("" ::: "memory");
        if (t + 1 < NT) {
            stage(t + 1, (t + 1) & 1);
            asm volatile("s_waitcnt vmcnt(4)" ::: "memory");   // t's 4 landed
        } else {
            asm volatile("s_waitcnt vmcnt(0)" ::: "memory");
        }
        __builtin_amdgcn_s_barrier();          // BAR-B: buf[t&1] valid for all waves
        asm volatile("" ::: "memory");

#pragma unroll
        for (int si = 0; si < 2; ++si) {
            if (t >= ntS[si]) continue;
            const int qmaxw = q0[si] + w * 32 + 31;
            if (j0 > qmaxw) continue;

            f32x4 sc[2][4];
            __builtin_amdgcn_s_setprio(1);
#pragma unroll
            for (int nt = 0; nt < 4; ++nt) {
                int krow = nt * 16 + lr;
                int swz = (krow & 7) << 3;
                bf16x8 a0 = *reinterpret_cast<const bf16x8*>(&KsB[krow * 64 + ((lg * 8) ^ swz)]);
                bf16x8 a1 = *reinterpret_cast<const bf16x8*>(&KsB[krow * 64 + ((32 + lg * 8) ^ swz)]);
#pragma unroll
                for (int qs = 0; qs < 2; ++qs) {
                    f32x4 tv = {};
                    tv = __builtin_amdgcn_mfma_f32_16x16x32_bf16(a0, aq[si][qs][0], tv, 0, 0, 0);
                    tv = __builtin_amdgcn_mfma_f32_16x16x32_bf16(a1, aq[si][qs][1], tv, 0, 0, 0);
                    sc[qs][nt] = tv;
                }
            }
            __builtin_amdgcn_s_setprio(0);

            s16x4 ap[2][4];
#pragma unroll
            for (int qs = 0; qs < 2; ++qs) {
                const int qrow = q0[si] + w * 32 + qs * 16 + lr;
                if (j0 + 63 > q0[si] + w * 32 + qs * 16) {
#pragma unroll
                    for (int nt = 0; nt < 4; ++nt)
#pragma unroll
                        for (int r = 0; r < 4; ++r) {
                            int kv = j0 + nt * 16 + lg * 4 + r;
                            if (kv > qrow) sc[qs][nt][r] = -1e30f;
                        }
                }
                float tmax = sc[qs][0][0];
#pragma unroll
                for (int nt = 0; nt < 4; ++nt)
#pragma unroll
                    for (int r = 0; r < 4; ++r) tmax = fmaxf(tmax, sc[qs][nt][r]);
                tmax = fmaxf(tmax, __shfl_xor(tmax, 16, 64));
                tmax = fmaxf(tmax, __shfl_xor(tmax, 32, 64));
                float mold = m_run[si][qs];
                if (!__all(tmax - mold <= 8.0f)) {
                    float mnew = fmaxf(mold, tmax);
                    float corr = exp2f(mold - mnew);
                    m_run[si][qs] = mnew;
                    l_run[si][qs] *= corr;
#pragma unroll
                    for (int r = 0; r < 4; ++r) {
                        float cr = __shfl(corr, (lane & 48) | (lg * 4 + r), 64);
#pragma unroll
                        for (int dt = 0; dt < 4; ++dt) acc[si][qs][dt][r] *= cr;
                    }
                }
                float mnow = m_run[si][qs];
                float rs = 0.f;
#pragma unroll
                for (int nt = 0; nt < 4; ++nt)
#pragma unroll
                    for (int r = 0; r < 4; ++r) {
                        float p = exp2f(sc[qs][nt][r] - mnow);
                        rs += p;
                        ap[qs][nt][r] = f2bf_s(p);
                    }
                rs += __shfl_xor(rs, 16, 64);
                rs += __shfl_xor(rs, 32, 64);
                l_run[si][qs] += rs;
            }

            __builtin_amdgcn_s_setprio(1);
#pragma unroll
            for (int dt = 0; dt < 4; ++dt) {
                int vrow = dt * 16 + lr;
                int vswz = (((vrow & 7) ^ (vrow >> 3)) & 7) << 3;
                s16x4 bv[4];
#pragma unroll
                for (int nt = 0; nt < 4; ++nt)
                    bv[nt] = *reinterpret_cast<const s16x4*>(&VtB[vrow * 64 + ((nt * 16 + lg * 4) ^ vswz)]);
#pragma unroll
                for (int qs = 0; qs < 2; ++qs)
#pragma unroll
                    for (int nt = 0; nt < 4; ++nt)
                        acc[si][qs][dt] = mfma16(ap[qs][nt], bv[nt], acc[si][qs][dt]);
            }
            __builtin_amdgcn_s_setprio(0);
        }
    }

#pragma unroll
    for (int si = 0; si < 2; ++si)
#pragma unroll
        for (int qs = 0; qs < 2; ++qs) {
            float inv = __builtin_amdgcn_rcpf(l_run[si][qs]);
#pragma unroll
            for (int r = 0; r < 4; ++r) {
                float invr = __shfl(inv, (lane & 48) | (lg * 4 + r), 64);
                int row = q0[si] + w * 32 + qs * 16 + lg * 4 + r;
#pragma unroll
                for (int dt = 0; dt < 4; ++dt)
                    O[base + (size_t)row * D_ + dt * 16 + lr] = (bf16)(acc[si][qs][dt][r] * invr);
            }
        }
}

// ---------------- launcher ----------------
extern "C" void kernel_launch(void* const* d_in, const int* in_sizes, int n_in,
                              void* d_out, int out_size, void* d_ws, size_t ws_size,
                              hipStream_t stream) {
    const float* x  = (const float*)d_in[0];
    const int*   tp = (const int*)d_in[1];
    const float* wq = (const float*)d_in[2];
    const float* wk = (const float*)d_in[3];
    const float* wv = (const float*)d_in[4];
    const float* wo = (const float*)d_in[5];

    bf16* ws = (bf16*)d_ws;
    bf16* Xbf = ws;
    bf16* Wqb = Xbf + (size_t)NTOK * D_;          // [3072][1024] packed Wq|Wk|Wv
    bf16* Wkb = Wqb + (size_t)D_ * D_;
    bf16* Wvb = Wkb + (size_t)D_ * D_;
    bf16* Wob = Wvb + (size_t)D_ * D_;
    bf16* Qr  = Wob + (size_t)D_ * D_;
    bf16* Kz  = Qr + (size_t)NTOK * D_;           // K, swizzled within head slices
    bf16* VT  = Kz + (size_t)NTOK * D_;           // V^T[b][h][tile][dd][kv']
    bf16* AO  = VT + (size_t)NTOK * D_;
    float2* tab = (float2*)(AO + (size_t)NTOK * D_);
    (void)ws_size; (void)in_sizes; (void)n_in; (void)out_size;
    (void)Wkb; (void)Wvb;

    {
        int ntot8 = (NTOK * D_ + 4 * D_ * D_) / 8;
        cvt_all<<<(ntot8 + 255) / 256, 256, 0, stream>>>(x, wq, wk, wv, wo, Xbf);
    }
    rope_table<<<(NTOK * 32 + 255) / 256, 256, 0, stream>>>(tp, tab);

    gemm_qkv<<<dim3(NTOK / 128, 24), 256, 0, stream>>>(Xbf, Wqb, Qr, Kz, VT, tab);

    flash_attn9<<<dim3(8, B_ * H_), 256, 0, stream>>>(Qr, Kz, VT, AO);

    gemm_out<<<dim3(NTOK / 128, D_ / 128), 256, 0, stream>>>(AO, Wob, (float*)d_out);
}

// Round 13
// 211.899 us; speedup vs baseline: 1.0099x; 1.0099x over previous
//
#include <hip/hip_runtime.h>
#include <hip/hip_bf16.h>
#include <cstdint>
#include <cstddef>

#define B_ 4
#define S_ 2048
#define D_ 1024
#define H_ 16
#define DK_ 64
#define NTOK (B_*S_)

typedef __bf16 bf16;
typedef __bf16 bf16x8 __attribute__((ext_vector_type(8)));
typedef short s16x4 __attribute__((ext_vector_type(4)));
typedef float f32x4 __attribute__((ext_vector_type(4)));

#define AS1 __attribute__((address_space(1)))
#define AS3 __attribute__((address_space(3)))

static __device__ __forceinline__ short f2bf_s(float f) {
    return __builtin_bit_cast(short, (__bf16)f);
}

static __device__ __forceinline__ f32x4 mfma16(s16x4 a, s16x4 b, f32x4 c) {
#if __has_builtin(__builtin_amdgcn_mfma_f32_16x16x16bf16_1k)
    return __builtin_amdgcn_mfma_f32_16x16x16bf16_1k(a, b, c, 0, 0, 0);
#else
    asm volatile("v_mfma_f32_16x16x16_bf16 %0, %1, %2, %0\n\ts_nop 7\n\ts_nop 7"
                 : "+v"(c) : "v"(a), "v"(b));
    return c;
#endif
}

// ---------------- fused fp32 -> bf16 convert: [X | Wq | Wk | Wv | Wo] ----------------
__global__ void cvt_all(const float* __restrict__ x, const float* __restrict__ wq,
                        const float* __restrict__ wk, const float* __restrict__ wv,
                        const float* __restrict__ wo, bf16* __restrict__ dst) {
    const int NX8 = NTOK * D_ / 8;
    const int W8 = D_ * D_ / 8;          // 131072 = 2^17
    int i = blockIdx.x * blockDim.x + threadIdx.x;
    if (i >= NX8 + 4 * W8) return;
    const float* src; int j;
    if (i < NX8) { src = x; j = i; }
    else {
        int k = i - NX8;
        int w = k >> 17;
        j = k & (W8 - 1);
        src = w == 0 ? wq : (w == 1 ? wk : (w == 2 ? wv : wo));
    }
    const float4* s4 = reinterpret_cast<const float4*>(src) + (size_t)j * 2;
    float4 a = s4[0], b = s4[1];
    bf16x8 o;
    o[0] = (bf16)a.x; o[1] = (bf16)a.y; o[2] = (bf16)a.z; o[3] = (bf16)a.w;
    o[4] = (bf16)b.x; o[5] = (bf16)b.y; o[6] = (bf16)b.z; o[7] = (bf16)b.w;
    reinterpret_cast<bf16x8*>(dst)[i] = o;
}

// ---------------- RoPE cos/sin table: [NTOK][32] float2 ----------------
__global__ void rope_table(const int* __restrict__ pos, float2* __restrict__ tab) {
    int i = blockIdx.x * blockDim.x + threadIdx.x;
    if (i >= NTOK * 32) return;
    int n = i >> 5, p = i & 31;
    float pf = (float)pos[n];
    float freq = powf(10000.0f, -(float)p * (1.0f / 32.0f));
    float ang = pf * freq;
    float s, c;
    sincosf(ang, &s, &c);
    tab[i] = make_float2(c, s);
}

// ---------------- 128x128 QKV GEMM, 2-phase interleave (T3), counted vmcnt ----------
// Phase 1: {ds af+bfr01, 16 MFMA}; stage-B(kt+1); BAR; Phase 2: {ds bfr23, 16 MFMA}.
// stage-A(kt+1) at kt top; vmcnt(4) proves kt's 8 loads landed (FIFO).
__global__ __launch_bounds__(256, 2)
void gemm_qkv(const bf16* __restrict__ A, const bf16* __restrict__ Bw,
              bf16* __restrict__ Qr, bf16* __restrict__ Kz, bf16* __restrict__ VT,
              const float2* __restrict__ tab) {
    const float SCL2E = 0.125f * 1.44269504088896340736f;
    constexpr int NKT = 16;
    __shared__ alignas(16) bf16 lds[2][(128 + 128) * 64];
    const int tid = threadIdx.x;
    const int lane = tid & 63;
    const int wid = tid >> 6;
    const int wm = wid >> 1, wn = wid & 1;
    const int lr = lane & 15, lg = lane >> 4;
    const int m0 = blockIdx.x * 128;
    const int n0g = blockIdx.y * 128;             // 0..3071

    f32x4 acc[4][4] = {};

    auto stageA = [&](int kt, int bufi) {
        bf16* dst = &lds[bufi][0];
#pragma unroll
        for (int j = 0; j < 4; ++j) {
            int flat = j * 256 + tid;
            int r = flat >> 3, c = flat & 7;
            const bf16* src = A + (size_t)(m0 + r) * 1024 + kt * 64 + ((c ^ (r & 7)) << 3);
            __builtin_amdgcn_global_load_lds((const AS1 uint32_t*)src,
                                             (AS3 uint32_t*)(dst + (size_t)flat * 8), 16, 0, 0);
        }
    };
    auto stageB = [&](int kt, int bufi) {
        bf16* dst = &lds[bufi][0] + 128 * 64;
#pragma unroll
        for (int j = 0; j < 4; ++j) {
            int flat = j * 256 + tid;
            int r = flat >> 3, c = flat & 7;
            const bf16* src = Bw + (size_t)(n0g + r) * 1024 + kt * 64 + ((c ^ (r & 7)) << 3);
            __builtin_amdgcn_global_load_lds((const AS1 uint32_t*)src,
                                             (AS3 uint32_t*)(dst + (size_t)flat * 8), 16, 0, 0);
        }
    };

    stageA(0, 0);
    stageB(0, 0);

    for (int kt = 0; kt < NKT; ++kt) {
        const bf16* bufA = &lds[kt & 1][0];
        const bf16* bufB = bufA + 128 * 64;

        asm volatile("" ::: "memory");
        __builtin_amdgcn_s_barrier();             // BAR-A: readers of buf[(kt+1)&1] done
        asm volatile("" ::: "memory");
        if (kt + 1 < NKT) {
            stageA(kt + 1, (kt + 1) & 1);
            asm volatile("s_waitcnt vmcnt(4)" ::: "memory");   // kt's 8 landed
        } else {
            asm volatile("s_waitcnt vmcnt(0)" ::: "memory");
        }
        __builtin_amdgcn_s_barrier();             // BAR-B: buf[kt&1] valid
        asm volatile("" ::: "memory");

        const int sx = lr & 7;
        bf16x8 af[4][2], bfr[4][2];
        // ---- phase 1: A frags + B frags 0-1, MFMA nf 0-1 ----
#pragma unroll
        for (int mf = 0; mf < 4; ++mf)
#pragma unroll
            for (int kh = 0; kh < 2; ++kh)
                af[mf][kh] = *reinterpret_cast<const bf16x8*>(
                    &bufA[(wm * 64 + mf * 16 + lr) * 64 + (((kh * 4 + lg) ^ sx) << 3)]);
#pragma unroll
        for (int nf = 0; nf < 2; ++nf)
#pragma unroll
            for (int kh = 0; kh < 2; ++kh)
                bfr[nf][kh] = *reinterpret_cast<const bf16x8*>(
                    &bufB[(wn * 64 + nf * 16 + lr) * 64 + (((kh * 4 + lg) ^ sx) << 3)]);
        __builtin_amdgcn_s_setprio(1);
#pragma unroll
        for (int mf = 0; mf < 4; ++mf)
#pragma unroll
            for (int nf = 0; nf < 2; ++nf)
#pragma unroll
                for (int kh = 0; kh < 2; ++kh)
                    acc[mf][nf] = __builtin_amdgcn_mfma_f32_16x16x32_bf16(af[mf][kh], bfr[nf][kh], acc[mf][nf], 0, 0, 0);
        __builtin_amdgcn_s_setprio(0);
        if (kt + 1 < NKT) stageB(kt + 1, (kt + 1) & 1);
        asm volatile("" ::: "memory");
        __builtin_amdgcn_s_barrier();             // BAR-C: phase boundary
        asm volatile("" ::: "memory");
        // ---- phase 2: B frags 2-3, MFMA nf 2-3 ----
#pragma unroll
        for (int nf = 2; nf < 4; ++nf)
#pragma unroll
            for (int kh = 0; kh < 2; ++kh)
                bfr[nf][kh] = *reinterpret_cast<const bf16x8*>(
                    &bufB[(wn * 64 + nf * 16 + lr) * 64 + (((kh * 4 + lg) ^ sx) << 3)]);
        __builtin_amdgcn_s_setprio(1);
#pragma unroll
        for (int mf = 0; mf < 4; ++mf)
#pragma unroll
            for (int nf = 2; nf < 4; ++nf)
#pragma unroll
                for (int kh = 0; kh < 2; ++kh)
                    acc[mf][nf] = __builtin_amdgcn_mfma_f32_16x16x32_bf16(af[mf][kh], bfr[nf][kh], acc[mf][nf], 0, 0, 0);
        __builtin_amdgcn_s_setprio(0);
    }

    // epilogue (unchanged from R12-verified): Q RoPE+scale, K swizzled, V^T packed
#pragma unroll
    for (int mf = 0; mf < 4; ++mf) {
#pragma unroll
        for (int nf = 0; nf < 4; ++nf) {
            int row0 = m0 + wm * 64 + mf * 16 + lg * 4;      // +r
            int colg = n0g + wn * 64 + nf * 16 + lr;
            int which = colg >> 10;                          // block-uniform
            int col = colg & 1023;
            if (which < 2) {
#pragma unroll
                for (int r = 0; r < 4; ++r) {
                    int row = row0 + r;
                    float v = acc[mf][nf][r];
                    float partner = __shfl_xor(v, 1, 64);
                    float2 cs = tab[(size_t)row * 32 + ((col >> 1) & 31)];
                    float o = (col & 1) ? fmaf(v, cs.x, partner * cs.y)
                                        : fmaf(v, cs.x, -partner * cs.y);
                    if (which == 0) {
                        Qr[(size_t)row * 1024 + col] = (bf16)(o * SCL2E);
                    } else {
                        int h = col >> 6, e = col & 63;
                        int e2 = e ^ ((row & 7) << 3);
                        Kz[(size_t)row * 1024 + h * 64 + e2] = (bf16)o;
                    }
                }
            } else {
                int h = col >> 6, dd = col & 63;
                int kvb = row0 & 63;
                int sw = (((dd & 7) ^ ((dd >> 3) & 7)) & 7) << 3;
                s16x4 pk;
#pragma unroll
                for (int r = 0; r < 4; ++r) pk[r] = f2bf_s(acc[mf][nf][r]);
                size_t addr = ((((size_t)((row0 >> 11) * 16 + h)) * 32 + ((row0 >> 6) & 31)) * 64 + dd) * 64
                              + (size_t)(kvb ^ sw);
                *reinterpret_cast<s16x4*>(&VT[addr]) = pk;
            }
        }
    }
}

// ---------------- output GEMM: 128x128, 2-phase interleave, fp32 out ----------------
__global__ __launch_bounds__(256, 2)
void gemm_out(const bf16* __restrict__ A, const bf16* __restrict__ Bw,
              float* __restrict__ Cp) {
    constexpr int NKT = 16;
    __shared__ alignas(16) bf16 lds[2][(128 + 128) * 64];
    const int tid = threadIdx.x;
    const int lane = tid & 63;
    const int wid = tid >> 6;
    const int wm = wid >> 1, wn = wid & 1;
    const int lr = lane & 15, lg = lane >> 4;
    const int m0 = blockIdx.x * 128;
    const int n0g = blockIdx.y * 128;

    f32x4 acc[4][4] = {};

    auto stageA = [&](int kt, int bufi) {
        bf16* dst = &lds[bufi][0];
#pragma unroll
        for (int j = 0; j < 4; ++j) {
            int flat = j * 256 + tid;
            int r = flat >> 3, c = flat & 7;
            const bf16* src = A + (size_t)(m0 + r) * 1024 + kt * 64 + ((c ^ (r & 7)) << 3);
            __builtin_amdgcn_global_load_lds((const AS1 uint32_t*)src,
                                             (AS3 uint32_t*)(dst + (size_t)flat * 8), 16, 0, 0);
        }
    };
    auto stageB = [&](int kt, int bufi) {
        bf16* dst = &lds[bufi][0] + 128 * 64;
#pragma unroll
        for (int j = 0; j < 4; ++j) {
            int flat = j * 256 + tid;
            int r = flat >> 3, c = flat & 7;
            const bf16* src = Bw + (size_t)(n0g + r) * 1024 + kt * 64 + ((c ^ (r & 7)) << 3);
            __builtin_amdgcn_global_load_lds((const AS1 uint32_t*)src,
                                             (AS3 uint32_t*)(dst + (size_t)flat * 8), 16, 0, 0);
        }
    };

    stageA(0, 0);
    stageB(0, 0);

    for (int kt = 0; kt < NKT; ++kt) {
        const bf16* bufA = &lds[kt & 1][0];
        const bf16* bufB = bufA + 128 * 64;

        asm volatile("" ::: "memory");
        __builtin_amdgcn_s_barrier();
        asm volatile("" ::: "memory");
        if (kt + 1 < NKT) {
            stageA(kt + 1, (kt + 1) & 1);
            asm volatile("s_waitcnt vmcnt(4)" ::: "memory");
        } else {
            asm volatile("s_waitcnt vmcnt(0)" ::: "memory");
        }
        __builtin_amdgcn_s_barrier();
        asm volatile("" ::: "memory");

        const int sx = lr & 7;
        bf16x8 af[4][2], bfr[4][2];
#pragma unroll
        for (int mf = 0; mf < 4; ++mf)
#pragma unroll
            for (int kh = 0; kh < 2; ++kh)
                af[mf][kh] = *reinterpret_cast<const bf16x8*>(
                    &bufA[(wm * 64 + mf * 16 + lr) * 64 + (((kh * 4 + lg) ^ sx) << 3)]);
#pragma unroll
        for (int nf = 0; nf < 2; ++nf)
#pragma unroll
            for (int kh = 0; kh < 2; ++kh)
                bfr[nf][kh] = *reinterpret_cast<const bf16x8*>(
                    &bufB[(wn * 64 + nf * 16 + lr) * 64 + (((kh * 4 + lg) ^ sx) << 3)]);
        __builtin_amdgcn_s_setprio(1);
#pragma unroll
        for (int mf = 0; mf < 4; ++mf)
#pragma unroll
            for (int nf = 0; nf < 2; ++nf)
#pragma unroll
                for (int kh = 0; kh < 2; ++kh)
                    acc[mf][nf] = __builtin_amdgcn_mfma_f32_16x16x32_bf16(af[mf][kh], bfr[nf][kh], acc[mf][nf], 0, 0, 0);
        __builtin_amdgcn_s_setprio(0);
        if (kt + 1 < NKT) stageB(kt + 1, (kt + 1) & 1);
        asm volatile("" ::: "memory");
        __builtin_amdgcn_s_barrier();
        asm volatile("" ::: "memory");
#pragma unroll
        for (int nf = 2; nf < 4; ++nf)
#pragma unroll
            for (int kh = 0; kh < 2; ++kh)
                bfr[nf][kh] = *reinterpret_cast<const bf16x8*>(
                    &bufB[(wn * 64 + nf * 16 + lr) * 64 + (((kh * 4 + lg) ^ sx) << 3)]);
        __builtin_amdgcn_s_setprio(1);
#pragma unroll
        for (int mf = 0; mf < 4; ++mf)
#pragma unroll
            for (int nf = 2; nf < 4; ++nf)
#pragma unroll
                for (int kh = 0; kh < 2; ++kh)
                    acc[mf][nf] = __builtin_amdgcn_mfma_f32_16x16x32_bf16(af[mf][kh], bfr[nf][kh], acc[mf][nf], 0, 0, 0);
        __builtin_amdgcn_s_setprio(0);
    }

#pragma unroll
    for (int mf = 0; mf < 4; ++mf)
#pragma unroll
        for (int nf = 0; nf < 4; ++nf)
#pragma unroll
            for (int r = 0; r < 4; ++r) {
                int row = m0 + wm * 64 + mf * 16 + lg * 4 + r;
                int colg = n0g + wn * 64 + nf * 16 + lr;
                Cp[(size_t)row * 1024 + colg] = acc[mf][nf][r];
            }
}

// ---------------- causal flash attention: strip double-pipeline (T15) ----------------
// Same staging/sync/layout as R12-verified flash_attn9; program order changed to
// QK(A),QK(B) -> SM(A),PV(A) -> SM(B),PV(B): SM(A) VALU issues under QK(B) MFMA
// latency; SM(B) overlaps PV(A). No barrier/layout change.
__global__ __launch_bounds__(256, 2)
void flash_attn10(const bf16* __restrict__ Q, const bf16* __restrict__ Kz,
                  const bf16* __restrict__ VT, bf16* __restrict__ O) {
    __shared__ bf16 Ks[2][64 * 64];
    __shared__ bf16 Vt[2][64 * 64];
    const int tid = threadIdx.x, lane = tid & 63, w = tid >> 6;
    const int lr = lane & 15, lg = lane >> 4;
    const int qtA = blockIdx.x;
    const int qtB = 15 - qtA;
    const int q0[2] = { qtA * 128, qtB * 128 };
    const int ntS[2] = { 2 * qtA + 2, 2 * qtB + 2 };
    const int NT = ntS[1];
    const int bh = blockIdx.y;
    const int b = bh >> 4, h = bh & 15;
    const size_t base = ((size_t)b * S_) * D_ + (size_t)h * DK_;
    const size_t vtbase = (size_t)bh * 32 * 4096;

    bf16x8 aq[2][2][2];
#pragma unroll
    for (int si = 0; si < 2; ++si)
#pragma unroll
        for (int qs = 0; qs < 2; ++qs) {
            int qrow = q0[si] + w * 32 + qs * 16 + lr;
            const bf16* qp = Q + base + (size_t)qrow * D_ + lg * 8;
            aq[si][qs][0] = *reinterpret_cast<const bf16x8*>(qp);
            aq[si][qs][1] = *reinterpret_cast<const bf16x8*>(qp + 32);
        }

    f32x4 acc[2][2][4] = {};
    float m_run[2][2] = {{-1e30f, -1e30f}, {-1e30f, -1e30f}};
    float l_run[2][2] = {{0.f, 0.f}, {0.f, 0.f}};

    const int sjj = tid >> 3;
    const int se0 = (tid & 7) * 8;

    auto stage = [&](int t, int bufi) {
        bf16* kd = Ks[bufi];
        bf16* vd = Vt[bufi];
#pragma unroll
        for (int i = 0; i < 2; ++i) {
            int jj = sjj + i * 32;
            const bf16* ksrc = Kz + base + (size_t)(t * 64 + jj) * 1024 + se0;
            __builtin_amdgcn_global_load_lds((const AS1 uint32_t*)ksrc,
                                             (AS3 uint32_t*)(kd + jj * 64 + se0), 16, 0, 0);
            const bf16* vsrc = VT + vtbase + (size_t)t * 4096 + jj * 64 + se0;
            __builtin_amdgcn_global_load_lds((const AS1 uint32_t*)vsrc,
                                             (AS3 uint32_t*)(vd + jj * 64 + se0), 16, 0, 0);
        }
    };

    stage(0, 0);

    for (int t = 0; t < NT; ++t) {
        const int j0 = t * 64;
        const bf16* KsB = Ks[t & 1];
        const bf16* VtB = Vt[t & 1];

        asm volatile("" ::: "memory");
        __builtin_amdgcn_s_barrier();
        asm volatile("" ::: "memory");
        if (t + 1 < NT) {
            stage(t + 1, (t + 1) & 1);
            asm volatile("s_waitcnt vmcnt(4)" ::: "memory");
        } else {
            asm volatile("s_waitcnt vmcnt(0)" ::: "memory");
        }
        __builtin_amdgcn_s_barrier();
        asm volatile("" ::: "memory");

        const bool act[2] = { t < ntS[0] && j0 <= q0[0] + w * 32 + 31,
                              j0 <= q0[1] + w * 32 + 31 };
        f32x4 sc[2][2][4];

        // ---- QK for both strips (MFMA issued back-to-back) ----
        __builtin_amdgcn_s_setprio(1);
#pragma unroll
        for (int si = 0; si < 2; ++si) {
            if (!act[si]) continue;
#pragma unroll
            for (int nt = 0; nt < 4; ++nt) {
                int krow = nt * 16 + lr;
                int swz = (krow & 7) << 3;
                bf16x8 a0 = *reinterpret_cast<const bf16x8*>(&KsB[krow * 64 + ((lg * 8) ^ swz)]);
                bf16x8 a1 = *reinterpret_cast<const bf16x8*>(&KsB[krow * 64 + ((32 + lg * 8) ^ swz)]);
#pragma unroll
                for (int qs = 0; qs < 2; ++qs) {
                    f32x4 tv = {};
                    tv = __builtin_amdgcn_mfma_f32_16x16x32_bf16(a0, aq[si][qs][0], tv, 0, 0, 0);
                    tv = __builtin_amdgcn_mfma_f32_16x16x32_bf16(a1, aq[si][qs][1], tv, 0, 0, 0);
                    sc[si][qs][nt] = tv;
                }
            }
        }
        __builtin_amdgcn_s_setprio(0);

        // ---- SM + PV per strip (SM(0) overlaps QK(1); SM(1) overlaps PV(0)) ----
#pragma unroll
        for (int si = 0; si < 2; ++si) {
            if (!act[si]) continue;

            s16x4 ap[2][4];
#pragma unroll
            for (int qs = 0; qs < 2; ++qs) {
                const int qrow = q0[si] + w * 32 + qs * 16 + lr;
                if (j0 + 63 > q0[si] + w * 32 + qs * 16) {
#pragma unroll
                    for (int nt = 0; nt < 4; ++nt)
#pragma unroll
                        for (int r = 0; r < 4; ++r) {
                            int kv = j0 + nt * 16 + lg * 4 + r;
                            if (kv > qrow) sc[si][qs][nt][r] = -1e30f;
                        }
                }
                float tmax = sc[si][qs][0][0];
#pragma unroll
                for (int nt = 0; nt < 4; ++nt)
#pragma unroll
                    for (int r = 0; r < 4; ++r) tmax = fmaxf(tmax, sc[si][qs][nt][r]);
                tmax = fmaxf(tmax, __shfl_xor(tmax, 16, 64));
                tmax = fmaxf(tmax, __shfl_xor(tmax, 32, 64));
                float mold = m_run[si][qs];
                if (!__all(tmax - mold <= 8.0f)) {
                    float mnew = fmaxf(mold, tmax);
                    float corr = exp2f(mold - mnew);
                    m_run[si][qs] = mnew;
                    l_run[si][qs] *= corr;
#pragma unroll
                    for (int r = 0; r < 4; ++r) {
                        float cr = __shfl(corr, (lane & 48) | (lg * 4 + r), 64);
#pragma unroll
                        for (int dt = 0; dt < 4; ++dt) acc[si][qs][dt][r] *= cr;
                    }
                }
                float mnow = m_run[si][qs];
                float rs = 0.f;
#pragma unroll
                for (int nt = 0; nt < 4; ++nt)
#pragma unroll
                    for (int r = 0; r < 4; ++r) {
                        float p = exp2f(sc[si][qs][nt][r] - mnow);
                        rs += p;
                        ap[qs][nt][r] = f2bf_s(p);
                    }
                rs += __shfl_xor(rs, 16, 64);
                rs += __shfl_xor(rs, 32, 64);
                l_run[si][qs] += rs;
            }

            __builtin_amdgcn_s_setprio(1);
#pragma unroll
            for (int dt = 0; dt < 4; ++dt) {
                int vrow = dt * 16 + lr;
                int vswz = (((vrow & 7) ^ (vrow >> 3)) & 7) << 3;
                s16x4 bv[4];
#pragma unroll
                for (int nt = 0; nt < 4; ++nt)
                    bv[nt] = *reinterpret_cast<const s16x4*>(&VtB[vrow * 64 + ((nt * 16 + lg * 4) ^ vswz)]);
#pragma unroll
                for (int qs = 0; qs < 2; ++qs)
#pragma unroll
                    for (int nt = 0; nt < 4; ++nt)
                        acc[si][qs][dt] = mfma16(ap[qs][nt], bv[nt], acc[si][qs][dt]);
            }
            __builtin_amdgcn_s_setprio(0);
        }
    }

#pragma unroll
    for (int si = 0; si < 2; ++si)
#pragma unroll
        for (int qs = 0; qs < 2; ++qs) {
            float inv = __builtin_amdgcn_rcpf(l_run[si][qs]);
#pragma unroll
            for (int r = 0; r < 4; ++r) {
                float invr = __shfl(inv, (lane & 48) | (lg * 4 + r), 64);
                int row = q0[si] + w * 32 + qs * 16 + lg * 4 + r;
#pragma unroll
                for (int dt = 0; dt < 4; ++dt)
                    O[base + (size_t)row * D_ + dt * 16 + lr] = (bf16)(acc[si][qs][dt][r] * invr);
            }
        }
}

// ---------------- launcher ----------------
extern "C" void kernel_launch(void* const* d_in, const int* in_sizes, int n_in,
                              void* d_out, int out_size, void* d_ws, size_t ws_size,
                              hipStream_t stream) {
    const float* x  = (const float*)d_in[0];
    const int*   tp = (const int*)d_in[1];
    const float* wq = (const float*)d_in[2];
    const float* wk = (const float*)d_in[3];
    const float* wv = (const float*)d_in[4];
    const float* wo = (const float*)d_in[5];

    bf16* ws = (bf16*)d_ws;
    bf16* Xbf = ws;
    bf16* Wqb = Xbf + (size_t)NTOK * D_;          // [3072][1024] packed Wq|Wk|Wv
    bf16* Wkb = Wqb + (size_t)D_ * D_;
    bf16* Wvb = Wkb + (size_t)D_ * D_;
    bf16* Wob = Wvb + (size_t)D_ * D_;
    bf16* Qr  = Wob + (size_t)D_ * D_;
    bf16* Kz  = Qr + (size_t)NTOK * D_;           // K, swizzled within head slices
    bf16* VT  = Kz + (size_t)NTOK * D_;           // V^T[b][h][tile][dd][kv']
    bf16* AO  = VT + (size_t)NTOK * D_;
    float2* tab = (float2*)(AO + (size_t)NTOK * D_);
    (void)ws_size; (void)in_sizes; (void)n_in; (void)out_size;
    (void)Wkb; (void)Wvb;

    {
        int ntot8 = (NTOK * D_ + 4 * D_ * D_) / 8;
        cvt_all<<<(ntot8 + 255) / 256, 256, 0, stream>>>(x, wq, wk, wv, wo, Xbf);
    }
    rope_table<<<(NTOK * 32 + 255) / 256, 256, 0, stream>>>(tp, tab);

    gemm_qkv<<<dim3(NTOK / 128, 24), 256, 0, stream>>>(Xbf, Wqb, Qr, Kz, VT, tab);

    flash_attn10<<<dim3(8, B_ * H_), 256, 0, stream>>>(Qr, Kz, VT, AO);

    gemm_out<<<dim3(NTOK / 128, D_ / 128), 256, 0, stream>>>(AO, Wob, (float*)d_out);
}

// Round 14
// 206.885 us; speedup vs baseline: 1.0343x; 1.0242x over previous
//
#include <hip/hip_runtime.h>
#include <hip/hip_bf16.h>
#include <cstdint>
#include <cstddef>

#define B_ 4
#define S_ 2048
#define D_ 1024
#define H_ 16
#define DK_ 64
#define NTOK (B_*S_)

typedef __bf16 bf16;
typedef __bf16 bf16x8 __attribute__((ext_vector_type(8)));
typedef short s16x4 __attribute__((ext_vector_type(4)));
typedef float f32x4 __attribute__((ext_vector_type(4)));

#define AS1 __attribute__((address_space(1)))
#define AS3 __attribute__((address_space(3)))

static __device__ __forceinline__ short f2bf_s(float f) {
    return __builtin_bit_cast(short, (__bf16)f);
}

static __device__ __forceinline__ f32x4 mfma16(s16x4 a, s16x4 b, f32x4 c) {
#if __has_builtin(__builtin_amdgcn_mfma_f32_16x16x16bf16_1k)
    return __builtin_amdgcn_mfma_f32_16x16x16bf16_1k(a, b, c, 0, 0, 0);
#else
    asm volatile("v_mfma_f32_16x16x16_bf16 %0, %1, %2, %0\n\ts_nop 7\n\ts_nop 7"
                 : "+v"(c) : "v"(a), "v"(b));
    return c;
#endif
}

// ---------------- fused fp32 -> bf16 convert: [X | Wq | Wk | Wv | Wo] ----------------
__global__ void cvt_all(const float* __restrict__ x, const float* __restrict__ wq,
                        const float* __restrict__ wk, const float* __restrict__ wv,
                        const float* __restrict__ wo, bf16* __restrict__ dst) {
    const int NX8 = NTOK * D_ / 8;
    const int W8 = D_ * D_ / 8;          // 131072 = 2^17
    int i = blockIdx.x * blockDim.x + threadIdx.x;
    if (i >= NX8 + 4 * W8) return;
    const float* src; int j;
    if (i < NX8) { src = x; j = i; }
    else {
        int k = i - NX8;
        int w = k >> 17;
        j = k & (W8 - 1);
        src = w == 0 ? wq : (w == 1 ? wk : (w == 2 ? wv : wo));
    }
    const float4* s4 = reinterpret_cast<const float4*>(src) + (size_t)j * 2;
    float4 a = s4[0], b = s4[1];
    bf16x8 o;
    o[0] = (bf16)a.x; o[1] = (bf16)a.y; o[2] = (bf16)a.z; o[3] = (bf16)a.w;
    o[4] = (bf16)b.x; o[5] = (bf16)b.y; o[6] = (bf16)b.z; o[7] = (bf16)b.w;
    reinterpret_cast<bf16x8*>(dst)[i] = o;
}

// ---------------- RoPE cos/sin table: [NTOK][32] float2 ----------------
__global__ void rope_table(const int* __restrict__ pos, float2* __restrict__ tab) {
    int i = blockIdx.x * blockDim.x + threadIdx.x;
    if (i >= NTOK * 32) return;
    int n = i >> 5, p = i & 31;
    float pf = (float)pos[n];
    float freq = powf(10000.0f, -(float)p * (1.0f / 32.0f));
    float ang = pf * freq;
    float s, c;
    sincosf(ang, &s, &c);
    tab[i] = make_float2(c, s);
}

// ---------------- 128x128 QKV GEMM, 2-phase interleave, counted vmcnt (R13) --------
__global__ __launch_bounds__(256, 2)
void gemm_qkv(const bf16* __restrict__ A, const bf16* __restrict__ Bw,
              bf16* __restrict__ Qr, bf16* __restrict__ Kz, bf16* __restrict__ VT,
              const float2* __restrict__ tab) {
    const float SCL2E = 0.125f * 1.44269504088896340736f;
    constexpr int NKT = 16;
    __shared__ alignas(16) bf16 lds[2][(128 + 128) * 64];
    const int tid = threadIdx.x;
    const int lane = tid & 63;
    const int wid = tid >> 6;
    const int wm = wid >> 1, wn = wid & 1;
    const int lr = lane & 15, lg = lane >> 4;
    const int m0 = blockIdx.x * 128;
    const int n0g = blockIdx.y * 128;             // 0..3071

    f32x4 acc[4][4] = {};

    auto stageA = [&](int kt, int bufi) {
        bf16* dst = &lds[bufi][0];
#pragma unroll
        for (int j = 0; j < 4; ++j) {
            int flat = j * 256 + tid;
            int r = flat >> 3, c = flat & 7;
            const bf16* src = A + (size_t)(m0 + r) * 1024 + kt * 64 + ((c ^ (r & 7)) << 3);
            __builtin_amdgcn_global_load_lds((const AS1 uint32_t*)src,
                                             (AS3 uint32_t*)(dst + (size_t)flat * 8), 16, 0, 0);
        }
    };
    auto stageB = [&](int kt, int bufi) {
        bf16* dst = &lds[bufi][0] + 128 * 64;
#pragma unroll
        for (int j = 0; j < 4; ++j) {
            int flat = j * 256 + tid;
            int r = flat >> 3, c = flat & 7;
            const bf16* src = Bw + (size_t)(n0g + r) * 1024 + kt * 64 + ((c ^ (r & 7)) << 3);
            __builtin_amdgcn_global_load_lds((const AS1 uint32_t*)src,
                                             (AS3 uint32_t*)(dst + (size_t)flat * 8), 16, 0, 0);
        }
    };

    stageA(0, 0);
    stageB(0, 0);

    for (int kt = 0; kt < NKT; ++kt) {
        const bf16* bufA = &lds[kt & 1][0];
        const bf16* bufB = bufA + 128 * 64;

        asm volatile("" ::: "memory");
        __builtin_amdgcn_s_barrier();             // BAR-A
        asm volatile("" ::: "memory");
        if (kt + 1 < NKT) {
            stageA(kt + 1, (kt + 1) & 1);
            asm volatile("s_waitcnt vmcnt(4)" ::: "memory");
        } else {
            asm volatile("s_waitcnt vmcnt(0)" ::: "memory");
        }
        __builtin_amdgcn_s_barrier();             // BAR-B
        asm volatile("" ::: "memory");

        const int sx = lr & 7;
        bf16x8 af[4][2], bfr[4][2];
#pragma unroll
        for (int mf = 0; mf < 4; ++mf)
#pragma unroll
            for (int kh = 0; kh < 2; ++kh)
                af[mf][kh] = *reinterpret_cast<const bf16x8*>(
                    &bufA[(wm * 64 + mf * 16 + lr) * 64 + (((kh * 4 + lg) ^ sx) << 3)]);
#pragma unroll
        for (int nf = 0; nf < 2; ++nf)
#pragma unroll
            for (int kh = 0; kh < 2; ++kh)
                bfr[nf][kh] = *reinterpret_cast<const bf16x8*>(
                    &bufB[(wn * 64 + nf * 16 + lr) * 64 + (((kh * 4 + lg) ^ sx) << 3)]);
        __builtin_amdgcn_s_setprio(1);
#pragma unroll
        for (int mf = 0; mf < 4; ++mf)
#pragma unroll
            for (int nf = 0; nf < 2; ++nf)
#pragma unroll
                for (int kh = 0; kh < 2; ++kh)
                    acc[mf][nf] = __builtin_amdgcn_mfma_f32_16x16x32_bf16(af[mf][kh], bfr[nf][kh], acc[mf][nf], 0, 0, 0);
        __builtin_amdgcn_s_setprio(0);
        if (kt + 1 < NKT) stageB(kt + 1, (kt + 1) & 1);
        asm volatile("" ::: "memory");
        __builtin_amdgcn_s_barrier();             // BAR-C
        asm volatile("" ::: "memory");
#pragma unroll
        for (int nf = 2; nf < 4; ++nf)
#pragma unroll
            for (int kh = 0; kh < 2; ++kh)
                bfr[nf][kh] = *reinterpret_cast<const bf16x8*>(
                    &bufB[(wn * 64 + nf * 16 + lr) * 64 + (((kh * 4 + lg) ^ sx) << 3)]);
        __builtin_amdgcn_s_setprio(1);
#pragma unroll
        for (int mf = 0; mf < 4; ++mf)
#pragma unroll
            for (int nf = 2; nf < 4; ++nf)
#pragma unroll
                for (int kh = 0; kh < 2; ++kh)
                    acc[mf][nf] = __builtin_amdgcn_mfma_f32_16x16x32_bf16(af[mf][kh], bfr[nf][kh], acc[mf][nf], 0, 0, 0);
        __builtin_amdgcn_s_setprio(0);
    }

    // epilogue: Q RoPE+scale, K swizzled, V^T packed (R12-verified)
#pragma unroll
    for (int mf = 0; mf < 4; ++mf) {
#pragma unroll
        for (int nf = 0; nf < 4; ++nf) {
            int row0 = m0 + wm * 64 + mf * 16 + lg * 4;      // +r
            int colg = n0g + wn * 64 + nf * 16 + lr;
            int which = colg >> 10;                          // block-uniform
            int col = colg & 1023;
            if (which < 2) {
#pragma unroll
                for (int r = 0; r < 4; ++r) {
                    int row = row0 + r;
                    float v = acc[mf][nf][r];
                    float partner = __shfl_xor(v, 1, 64);
                    float2 cs = tab[(size_t)row * 32 + ((col >> 1) & 31)];
                    float o = (col & 1) ? fmaf(v, cs.x, partner * cs.y)
                                        : fmaf(v, cs.x, -partner * cs.y);
                    if (which == 0) {
                        Qr[(size_t)row * 1024 + col] = (bf16)(o * SCL2E);
                    } else {
                        int h = col >> 6, e = col & 63;
                        int e2 = e ^ ((row & 7) << 3);
                        Kz[(size_t)row * 1024 + h * 64 + e2] = (bf16)o;
                    }
                }
            } else {
                int h = col >> 6, dd = col & 63;
                int kvb = row0 & 63;
                int sw = (((dd & 7) ^ ((dd >> 3) & 7)) & 7) << 3;
                s16x4 pk;
#pragma unroll
                for (int r = 0; r < 4; ++r) pk[r] = f2bf_s(acc[mf][nf][r]);
                size_t addr = ((((size_t)((row0 >> 11) * 16 + h)) * 32 + ((row0 >> 6) & 31)) * 64 + dd) * 64
                              + (size_t)(kvb ^ sw);
                *reinterpret_cast<s16x4*>(&VT[addr]) = pk;
            }
        }
    }
}

// ---------------- output GEMM: 128x128, 2-phase interleave, fp32 out (R13) ----------
__global__ __launch_bounds__(256, 2)
void gemm_out(const bf16* __restrict__ A, const bf16* __restrict__ Bw,
              float* __restrict__ Cp) {
    constexpr int NKT = 16;
    __shared__ alignas(16) bf16 lds[2][(128 + 128) * 64];
    const int tid = threadIdx.x;
    const int lane = tid & 63;
    const int wid = tid >> 6;
    const int wm = wid >> 1, wn = wid & 1;
    const int lr = lane & 15, lg = lane >> 4;
    const int m0 = blockIdx.x * 128;
    const int n0g = blockIdx.y * 128;

    f32x4 acc[4][4] = {};

    auto stageA = [&](int kt, int bufi) {
        bf16* dst = &lds[bufi][0];
#pragma unroll
        for (int j = 0; j < 4; ++j) {
            int flat = j * 256 + tid;
            int r = flat >> 3, c = flat & 7;
            const bf16* src = A + (size_t)(m0 + r) * 1024 + kt * 64 + ((c ^ (r & 7)) << 3);
            __builtin_amdgcn_global_load_lds((const AS1 uint32_t*)src,
                                             (AS3 uint32_t*)(dst + (size_t)flat * 8), 16, 0, 0);
        }
    };
    auto stageB = [&](int kt, int bufi) {
        bf16* dst = &lds[bufi][0] + 128 * 64;
#pragma unroll
        for (int j = 0; j < 4; ++j) {
            int flat = j * 256 + tid;
            int r = flat >> 3, c = flat & 7;
            const bf16* src = Bw + (size_t)(n0g + r) * 1024 + kt * 64 + ((c ^ (r & 7)) << 3);
            __builtin_amdgcn_global_load_lds((const AS1 uint32_t*)src,
                                             (AS3 uint32_t*)(dst + (size_t)flat * 8), 16, 0, 0);
        }
    };

    stageA(0, 0);
    stageB(0, 0);

    for (int kt = 0; kt < NKT; ++kt) {
        const bf16* bufA = &lds[kt & 1][0];
        const bf16* bufB = bufA + 128 * 64;

        asm volatile("" ::: "memory");
        __builtin_amdgcn_s_barrier();
        asm volatile("" ::: "memory");
        if (kt + 1 < NKT) {
            stageA(kt + 1, (kt + 1) & 1);
            asm volatile("s_waitcnt vmcnt(4)" ::: "memory");
        } else {
            asm volatile("s_waitcnt vmcnt(0)" ::: "memory");
        }
        __builtin_amdgcn_s_barrier();
        asm volatile("" ::: "memory");

        const int sx = lr & 7;
        bf16x8 af[4][2], bfr[4][2];
#pragma unroll
        for (int mf = 0; mf < 4; ++mf)
#pragma unroll
            for (int kh = 0; kh < 2; ++kh)
                af[mf][kh] = *reinterpret_cast<const bf16x8*>(
                    &bufA[(wm * 64 + mf * 16 + lr) * 64 + (((kh * 4 + lg) ^ sx) << 3)]);
#pragma unroll
        for (int nf = 0; nf < 2; ++nf)
#pragma unroll
            for (int kh = 0; kh < 2; ++kh)
                bfr[nf][kh] = *reinterpret_cast<const bf16x8*>(
                    &bufB[(wn * 64 + nf * 16 + lr) * 64 + (((kh * 4 + lg) ^ sx) << 3)]);
        __builtin_amdgcn_s_setprio(1);
#pragma unroll
        for (int mf = 0; mf < 4; ++mf)
#pragma unroll
            for (int nf = 0; nf < 2; ++nf)
#pragma unroll
                for (int kh = 0; kh < 2; ++kh)
                    acc[mf][nf] = __builtin_amdgcn_mfma_f32_16x16x32_bf16(af[mf][kh], bfr[nf][kh], acc[mf][nf], 0, 0, 0);
        __builtin_amdgcn_s_setprio(0);
        if (kt + 1 < NKT) stageB(kt + 1, (kt + 1) & 1);
        asm volatile("" ::: "memory");
        __builtin_amdgcn_s_barrier();
        asm volatile("" ::: "memory");
#pragma unroll
        for (int nf = 2; nf < 4; ++nf)
#pragma unroll
            for (int kh = 0; kh < 2; ++kh)
                bfr[nf][kh] = *reinterpret_cast<const bf16x8*>(
                    &bufB[(wn * 64 + nf * 16 + lr) * 64 + (((kh * 4 + lg) ^ sx) << 3)]);
        __builtin_amdgcn_s_setprio(1);
#pragma unroll
        for (int mf = 0; mf < 4; ++mf)
#pragma unroll
            for (int nf = 2; nf < 4; ++nf)
#pragma unroll
                for (int kh = 0; kh < 2; ++kh)
                    acc[mf][nf] = __builtin_amdgcn_mfma_f32_16x16x32_bf16(af[mf][kh], bfr[nf][kh], acc[mf][nf], 0, 0, 0);
        __builtin_amdgcn_s_setprio(0);
    }

#pragma unroll
    for (int mf = 0; mf < 4; ++mf)
#pragma unroll
        for (int nf = 0; nf < 4; ++nf)
#pragma unroll
            for (int r = 0; r < 4; ++r) {
                int row = m0 + wm * 64 + mf * 16 + lg * 4 + r;
                int colg = n0g + wn * 64 + nf * 16 + lr;
                Cp[(size_t)row * 1024 + colg] = acc[mf][nf][r];
            }
}

// ---------------- causal flash attention: ones-column l-sum + cvt_pk ----------------
// Same staging/sync/layout/QK-PV as R13-verified flash_attn10. Softmax changes:
// (1) rs row-sum moved to MFMA pipe via B=ones frag: l_acc[si][qs] accumulates
//     Sum(P) in the SAME C-layout as acc (row=lg*4+r) -> rescale reuses cr,
//     epilogue loses its shfl. Deletes 32 VALU adds + 2 shfl per strip.
// (2) p->bf16 via v_cvt_pk_bf16_f32 pairs (16 ops replace 32 scalar cvts).
__global__ __launch_bounds__(256, 2)
void flash_attn11(const bf16* __restrict__ Q, const bf16* __restrict__ Kz,
                  const bf16* __restrict__ VT, bf16* __restrict__ O) {
    __shared__ bf16 Ks[2][64 * 64];
    __shared__ bf16 Vt[2][64 * 64];
    const int tid = threadIdx.x, lane = tid & 63, w = tid >> 6;
    const int lr = lane & 15, lg = lane >> 4;
    const int qtA = blockIdx.x;
    const int qtB = 15 - qtA;
    const int q0[2] = { qtA * 128, qtB * 128 };
    const int ntS[2] = { 2 * qtA + 2, 2 * qtB + 2 };
    const int NT = ntS[1];
    const int bh = blockIdx.y;
    const int b = bh >> 4, h = bh & 15;
    const size_t base = ((size_t)b * S_) * D_ + (size_t)h * DK_;
    const size_t vtbase = (size_t)bh * 32 * 4096;

    bf16x8 aq[2][2][2];
#pragma unroll
    for (int si = 0; si < 2; ++si)
#pragma unroll
        for (int qs = 0; qs < 2; ++qs) {
            int qrow = q0[si] + w * 32 + qs * 16 + lr;
            const bf16* qp = Q + base + (size_t)qrow * D_ + lg * 8;
            aq[si][qs][0] = *reinterpret_cast<const bf16x8*>(qp);
            aq[si][qs][1] = *reinterpret_cast<const bf16x8*>(qp + 32);
        }

    f32x4 acc[2][2][4] = {};
    f32x4 l_acc[2][2] = {};                       // Sum(P) in acc C-layout
    float m_run[2][2] = {{-1e30f, -1e30f}, {-1e30f, -1e30f}};

    // B = all-ones bf16 frag for the l-sum MFMA
    const short ONEB = (short)0x3F80;
    const s16x4 ones = { ONEB, ONEB, ONEB, ONEB };

    const int sjj = tid >> 3;
    const int se0 = (tid & 7) * 8;

    auto stage = [&](int t, int bufi) {
        bf16* kd = Ks[bufi];
        bf16* vd = Vt[bufi];
#pragma unroll
        for (int i = 0; i < 2; ++i) {
            int jj = sjj + i * 32;
            const bf16* ksrc = Kz + base + (size_t)(t * 64 + jj) * 1024 + se0;
            __builtin_amdgcn_global_load_lds((const AS1 uint32_t*)ksrc,
                                             (AS3 uint32_t*)(kd + jj * 64 + se0), 16, 0, 0);
            const bf16* vsrc = VT + vtbase + (size_t)t * 4096 + jj * 64 + se0;
            __builtin_amdgcn_global_load_lds((const AS1 uint32_t*)vsrc,
                                             (AS3 uint32_t*)(vd + jj * 64 + se0), 16, 0, 0);
        }
    };

    stage(0, 0);

    for (int t = 0; t < NT; ++t) {
        const int j0 = t * 64;
        const bf16* KsB = Ks[t & 1];
        const bf16* VtB = Vt[t & 1];

        asm volatile("" ::: "memory");
        __builtin_amdgcn_s_barrier();
        asm volatile("" ::: "memory");
        if (t + 1 < NT) {
            stage(t + 1, (t + 1) & 1);
            asm volatile("s_waitcnt vmcnt(4)" ::: "memory");
        } else {
            asm volatile("s_waitcnt vmcnt(0)" ::: "memory");
        }
        __builtin_amdgcn_s_barrier();
        asm volatile("" ::: "memory");

        const bool act[2] = { t < ntS[0] && j0 <= q0[0] + w * 32 + 31,
                              j0 <= q0[1] + w * 32 + 31 };
        f32x4 sc[2][2][4];

        // ---- QK for both strips ----
        __builtin_amdgcn_s_setprio(1);
#pragma unroll
        for (int si = 0; si < 2; ++si) {
            if (!act[si]) continue;
#pragma unroll
            for (int nt = 0; nt < 4; ++nt) {
                int krow = nt * 16 + lr;
                int swz = (krow & 7) << 3;
                bf16x8 a0 = *reinterpret_cast<const bf16x8*>(&KsB[krow * 64 + ((lg * 8) ^ swz)]);
                bf16x8 a1 = *reinterpret_cast<const bf16x8*>(&KsB[krow * 64 + ((32 + lg * 8) ^ swz)]);
#pragma unroll
                for (int qs = 0; qs < 2; ++qs) {
                    f32x4 tv = {};
                    tv = __builtin_amdgcn_mfma_f32_16x16x32_bf16(a0, aq[si][qs][0], tv, 0, 0, 0);
                    tv = __builtin_amdgcn_mfma_f32_16x16x32_bf16(a1, aq[si][qs][1], tv, 0, 0, 0);
                    sc[si][qs][nt] = tv;
                }
            }
        }
        __builtin_amdgcn_s_setprio(0);

        // ---- SM + PV per strip ----
#pragma unroll
        for (int si = 0; si < 2; ++si) {
            if (!act[si]) continue;

            s16x4 ap[2][4];
#pragma unroll
            for (int qs = 0; qs < 2; ++qs) {
                const int qrow = q0[si] + w * 32 + qs * 16 + lr;
                if (j0 + 63 > q0[si] + w * 32 + qs * 16) {
#pragma unroll
                    for (int nt = 0; nt < 4; ++nt)
#pragma unroll
                        for (int r = 0; r < 4; ++r) {
                            int kv = j0 + nt * 16 + lg * 4 + r;
                            if (kv > qrow) sc[si][qs][nt][r] = -1e30f;
                        }
                }
                float tmax = sc[si][qs][0][0];
#pragma unroll
                for (int nt = 0; nt < 4; ++nt)
#pragma unroll
                    for (int r = 0; r < 4; ++r) tmax = fmaxf(tmax, sc[si][qs][nt][r]);
                tmax = fmaxf(tmax, __shfl_xor(tmax, 16, 64));
                tmax = fmaxf(tmax, __shfl_xor(tmax, 32, 64));
                float mold = m_run[si][qs];
                if (!__all(tmax - mold <= 8.0f)) {
                    float mnew = fmaxf(mold, tmax);
                    float corr = exp2f(mold - mnew);
                    m_run[si][qs] = mnew;
#pragma unroll
                    for (int r = 0; r < 4; ++r) {
                        float cr = __shfl(corr, (lane & 48) | (lg * 4 + r), 64);
                        l_acc[si][qs][r] *= cr;
#pragma unroll
                        for (int dt = 0; dt < 4; ++dt) acc[si][qs][dt][r] *= cr;
                    }
                }
                float mnow = m_run[si][qs];
#pragma unroll
                for (int nt = 0; nt < 4; ++nt) {
                    float p0 = exp2f(sc[si][qs][nt][0] - mnow);
                    float p1 = exp2f(sc[si][qs][nt][1] - mnow);
                    float p2 = exp2f(sc[si][qs][nt][2] - mnow);
                    float p3 = exp2f(sc[si][qs][nt][3] - mnow);
                    int ulo, uhi;
                    asm("v_cvt_pk_bf16_f32 %0, %1, %2" : "=v"(ulo) : "v"(p0), "v"(p1));
                    asm("v_cvt_pk_bf16_f32 %0, %1, %2" : "=v"(uhi) : "v"(p2), "v"(p3));
                    int2 pr; pr.x = ulo; pr.y = uhi;
                    ap[qs][nt] = __builtin_bit_cast(s16x4, pr);
                }
            }

            // PV + l-sum (ones column) on the MFMA pipe
            __builtin_amdgcn_s_setprio(1);
#pragma unroll
            for (int qs = 0; qs < 2; ++qs)
#pragma unroll
                for (int nt = 0; nt < 4; ++nt)
                    l_acc[si][qs] = mfma16(ap[qs][nt], ones, l_acc[si][qs]);
#pragma unroll
            for (int dt = 0; dt < 4; ++dt) {
                int vrow = dt * 16 + lr;
                int vswz = (((vrow & 7) ^ (vrow >> 3)) & 7) << 3;
                s16x4 bv[4];
#pragma unroll
                for (int nt = 0; nt < 4; ++nt)
                    bv[nt] = *reinterpret_cast<const s16x4*>(&VtB[vrow * 64 + ((nt * 16 + lg * 4) ^ vswz)]);
#pragma unroll
                for (int qs = 0; qs < 2; ++qs)
#pragma unroll
                    for (int nt = 0; nt < 4; ++nt)
                        acc[si][qs][dt] = mfma16(ap[qs][nt], bv[nt], acc[si][qs][dt]);
            }
            __builtin_amdgcn_s_setprio(0);
        }
    }

    // epilogue: l_acc is already in acc layout -> direct per-r rcp, no shfl
#pragma unroll
    for (int si = 0; si < 2; ++si)
#pragma unroll
        for (int qs = 0; qs < 2; ++qs)
#pragma unroll
            for (int r = 0; r < 4; ++r) {
                float invr = __builtin_amdgcn_rcpf(l_acc[si][qs][r]);
                int row = q0[si] + w * 32 + qs * 16 + lg * 4 + r;
#pragma unroll
                for (int dt = 0; dt < 4; ++dt)
                    O[base + (size_t)row * D_ + dt * 16 + lr] = (bf16)(acc[si][qs][dt][r] * invr);
            }
}

// ---------------- launcher ----------------
extern "C" void kernel_launch(void* const* d_in, const int* in_sizes, int n_in,
                              void* d_out, int out_size, void* d_ws, size_t ws_size,
                              hipStream_t stream) {
    const float* x  = (const float*)d_in[0];
    const int*   tp = (const int*)d_in[1];
    const float* wq = (const float*)d_in[2];
    const float* wk = (const float*)d_in[3];
    const float* wv = (const float*)d_in[4];
    const float* wo = (const float*)d_in[5];

    bf16* ws = (bf16*)d_ws;
    bf16* Xbf = ws;
    bf16* Wqb = Xbf + (size_t)NTOK * D_;          // [3072][1024] packed Wq|Wk|Wv
    bf16* Wkb = Wqb + (size_t)D_ * D_;
    bf16* Wvb = Wkb + (size_t)D_ * D_;
    bf16* Wob = Wvb + (size_t)D_ * D_;
    bf16* Qr  = Wob + (size_t)D_ * D_;
    bf16* Kz  = Qr + (size_t)NTOK * D_;           // K, swizzled within head slices
    bf16* VT  = Kz + (size_t)NTOK * D_;           // V^T[b][h][tile][dd][kv']
    bf16* AO  = VT + (size_t)NTOK * D_;
    float2* tab = (float2*)(AO + (size_t)NTOK * D_);
    (void)ws_size; (void)in_sizes; (void)n_in; (void)out_size;
    (void)Wkb; (void)Wvb;

    {
        int ntot8 = (NTOK * D_ + 4 * D_ * D_) / 8;
        cvt_all<<<(ntot8 + 255) / 256, 256, 0, stream>>>(x, wq, wk, wv, wo, Xbf);
    }
    rope_table<<<(NTOK * 32 + 255) / 256, 256, 0, stream>>>(tp, tab);

    gemm_qkv<<<dim3(NTOK / 128, 24), 256, 0, stream>>>(Xbf, Wqb, Qr, Kz, VT, tab);

    flash_attn11<<<dim3(8, B_ * H_), 256, 0, stream>>>(Qr, Kz, VT, AO);

    gemm_out<<<dim3(NTOK / 128, D_ / 128), 256, 0, stream>>>(AO, Wob, (float*)d_out);
}